// Round 8
// baseline (192.412 us; speedup 1.0000x reference)
//
#include <hip/hip_runtime.h>
#include <cstdint>

// Fused single-head attention, B=4 S=2048 D=1024, fp32 in/out, bf16 MFMA compute.
// Pipeline: cast/pack -> QKV GEMM (v transposed) -> scores GEMM -> softmax -> PV GEMM.
// GEMM engine (R8): proven 128x128 / 4-wave structure (best measured in-session, R1)
// + T3/T4-minimal pipeline: BK=32, 3-slot LDS ring (48 KB -> 3 blocks/CU),
// stage 2 tiles ahead, ONE barrier per K-step, counted vmcnt(4) (never 0
// mid-loop). Paired-row XOR swizzle (measured 0 bank conflicts in R3/R4),
// staged via linear global_load_lds + inverse-swizzled global source.
// WAR safety: iter t's ds_reads are lgkm-drained before its MFMAs (data dep),
// hence before barrier(t); the overwriting stage (tile t+3, same slot) is
// issued after barrier(t). RAW: vmcnt(4) at iter t leaves only stage(t+2) in
// flight -> stage(t+1) landed before barrier(t).

typedef unsigned short u16;
typedef __attribute__((ext_vector_type(4))) float f32x4;
typedef __attribute__((ext_vector_type(8))) __bf16 bf16x8;

#define AS1(p) ((const __attribute__((address_space(1))) void*)(p))
#define AS3(p) ((__attribute__((address_space(3))) void*)(p))

#define SEQ 2048
#define DM 1024

// ---------- bf16 bit helpers ----------
__device__ __forceinline__ u16 f2b(float f) {
  uint32_t u = __builtin_bit_cast(uint32_t, f);
  u += 0x7FFFu + ((u >> 16) & 1u);   // RNE
  return (u16)(u >> 16);
}
__device__ __forceinline__ float b2f(uint32_t bits16) {
  return __builtin_bit_cast(float, bits16 << 16);
}

// ---------- converts ----------
__global__ __launch_bounds__(256) void cvt_x_kernel(const float* __restrict__ x,
                                                    u16* __restrict__ xb) {
  int i = (blockIdx.x * 256 + threadIdx.x) * 4;
  float4 v = *(const float4*)(x + i);
  ushort4 o;
  o.x = f2b(v.x); o.y = f2b(v.y); o.z = f2b(v.z); o.w = f2b(v.w);
  *(ushort4*)(xb + i) = o;
}

__global__ __launch_bounds__(256) void pack_w_kernel(const float* __restrict__ Wq,
                                                     const float* __restrict__ Wk,
                                                     const float* __restrict__ Wv,
                                                     u16* __restrict__ wcat) {
  int i = (blockIdx.x * 256 + threadIdx.x) * 4;   // over 3*2^20 elems
  const float* src;
  int j;
  if (i < (1 << 20))      { src = Wq; j = i; }
  else if (i < (2 << 20)) { src = Wk; j = i - (1 << 20); }
  else                    { src = Wv; j = i - (2 << 20); }
  float4 v = *(const float4*)(src + j);
  ushort4 o;
  o.x = f2b(v.x); o.y = f2b(v.y); o.z = f2b(v.z); o.w = f2b(v.w);
  *(ushort4*)(wcat + i) = o;
}

// ---------- 3-ring pipelined GEMM engine ----------
// Tile 128x128, 4 waves (2x2), per-wave 64x64 = acc[4][4] 16x16 frags, BK=32.
// LDS slot s (s=0,1,2): A region at s*16384, B region at s*16384+8192.
// Region = 128 rows x 32 cols bf16 (8 KB), paired-row swizzled:
//   byte(row, ch16) = (row>>1)*128 + ((((row&1)*4 + ch) ^ ((row>>1)&7))*16
// Frag read (lane l: row fr=l&15 of a 16-row group, k-chunk ch=l>>4) hits each
// 16B slot exactly twice -> 2 lanes/bank = free (measured 0 conflicts, R3/R4).

template <int T>
__device__ __forceinline__ void gemm3r(const u16* __restrict__ A,
                                       const u16* __restrict__ Bt,
                                       int lda, int ldb, char* lds,
                                       f32x4 (&acc)[4][4], int tid) {
  const int l = tid & 63, w = tid >> 6;
  const int wm = w >> 1, wn = w & 1;
  const int fr = l & 15, ch = l >> 4;
  const int tb = ((fr >> 1) << 7) + (((((fr & 1) << 2) | ch) ^ ((fr >> 1) & 7)) << 4);
  const int wlin = w * 1024;               // wave-uniform LDS base within region

  // staging: linear LDS byte o = j*4096 + tid*16 within an 8KB region;
  // inverse swizzle -> global element so reads see the swizzled layout.
  int aoff[2], boff[2];
#pragma unroll
  for (int j = 0; j < 2; ++j) {
    int o  = j * 4096 + tid * 16;
    int rp = o >> 7;
    int cl = ((o >> 4) & 7) ^ (rp & 7);
    aoff[j] = (rp * 2 + (cl >> 2)) * lda + (cl & 3) * 8;
    boff[j] = (rp * 2 + (cl >> 2)) * ldb + (cl & 3) * 8;
  }

  auto stage = [&](int t, int slot) {
    const int ke = t * 32;
#pragma unroll
    for (int j = 0; j < 2; ++j)
      __builtin_amdgcn_global_load_lds(AS1(A + aoff[j] + ke),
          AS3(lds + slot * 16384 + j * 4096 + wlin), 16, 0, 0);
#pragma unroll
    for (int j = 0; j < 2; ++j)
      __builtin_amdgcn_global_load_lds(AS1(Bt + boff[j] + ke),
          AS3(lds + slot * 16384 + 8192 + j * 4096 + wlin), 16, 0, 0);
  };

  stage(0, 0);
  stage(1, 1);
#pragma unroll
  for (int m = 0; m < 4; ++m)
#pragma unroll
    for (int n = 0; n < 4; ++n)
#pragma unroll
      for (int j = 0; j < 4; ++j) acc[m][n][j] = 0.f;
  asm volatile("s_waitcnt vmcnt(4)" ::: "memory");
  __builtin_amdgcn_s_barrier();

  int sR = 0, sS = 2;
  for (int t = 0; t < T; ++t) {
    if (t + 2 < T) stage(t + 2, sS);
    const char* la = lds + sR * 16384 + wm * 4096 + tb;
    const char* lb = lds + sR * 16384 + 8192 + wn * 4096 + tb;
    bf16x8 af[4], bf[4];
#pragma unroll
    for (int m = 0; m < 4; ++m) af[m] = *(const bf16x8*)(la + m * 1024);
#pragma unroll
    for (int n = 0; n < 4; ++n) bf[n] = *(const bf16x8*)(lb + n * 1024);
    __builtin_amdgcn_s_setprio(1);
#pragma unroll
    for (int m = 0; m < 4; ++m)
#pragma unroll
      for (int n = 0; n < 4; ++n)
        acc[m][n] = __builtin_amdgcn_mfma_f32_16x16x32_bf16(af[m], bf[n],
                                                            acc[m][n], 0, 0, 0);
    __builtin_amdgcn_s_setprio(0);
    if (t < T - 1) {
      if (t + 2 < T) asm volatile("s_waitcnt vmcnt(4)" ::: "memory");
      else           asm volatile("s_waitcnt vmcnt(0)" ::: "memory");
      __builtin_amdgcn_s_barrier();
    }
    sR = (sR + 1 == 3) ? 0 : sR + 1;
    sS = (sS + 1 == 3) ? 0 : sS + 1;
  }
}

// ---------- QKV GEMM: [8192 x 3072] = xb[8192x1024] * wcat[3072x1024]^T + bias ----------
// Tile 128x128; grid 1536 = 64(m) x 24(n); XCD-bijective swizzle (1536 = 8*192).
__global__ __launch_bounds__(256, 3) void qkv_gemm(const u16* __restrict__ xb,
                                                   const u16* __restrict__ wcat,
                                                   const float* __restrict__ bq,
                                                   const float* __restrict__ bk,
                                                   const float* __restrict__ bv,
                                                   u16* __restrict__ qb,
                                                   u16* __restrict__ kb,
                                                   u16* __restrict__ vtb) {
  __shared__ __align__(16) char lds[49152];
  const int tid = threadIdx.x;
  const int lin = blockIdx.x;
  const int wgid = (lin & 7) * 192 + (lin >> 3);
  const int bx = wgid % 24, by = wgid / 24;
  const int bm = by * 128, bn = bx * 128;
  f32x4 acc[4][4];
  gemm3r<32>(xb + bm * 1024, wcat + bn * 1024, 1024, 1024, lds, acc, tid);
  const int l = tid & 63, w = tid >> 6;
  const int wm = w >> 1, wn = w & 1;
  const int which = bn >> 10;               // uniform per block (128 | 1024)
  const float* bias = (which == 0) ? bq : (which == 1) ? bk : bv;
#pragma unroll
  for (int m = 0; m < 4; ++m)
#pragma unroll
    for (int n = 0; n < 4; ++n) {
      int col = bn + wn * 64 + n * 16 + (l & 15);
      int e = col & 1023;
      float bval = bias[e];
#pragma unroll
      for (int j = 0; j < 4; ++j) {
        int row = bm + wm * 64 + m * 16 + (l >> 4) * 4 + j;
        u16 hb = f2b(acc[m][n][j] + bval);
        if (which == 0)      qb[row * 1024 + e] = hb;
        else if (which == 1) kb[row * 1024 + e] = hb;
        else { int b = row >> 11, s = row & 2047; vtb[(b << 21) + e * 2048 + s] = hb; }
      }
    }
}

// ---------- scores GEMM per batch: sb = (q * k^T) / 32, bf16 ----------
// Grid 1024 = 4 batches x 16 x 16; XCD swizzle (1024 = 8*128).
__global__ __launch_bounds__(256, 3) void scores_gemm(const u16* __restrict__ qb,
                                                      const u16* __restrict__ kb,
                                                      u16* __restrict__ sb) {
  __shared__ __align__(16) char lds[49152];
  const int tid = threadIdx.x;
  const int lin = blockIdx.x;
  const int wgid = (lin & 7) * 128 + (lin >> 3);
  const int b = wgid >> 8, r = wgid & 255;
  const int by = r >> 4, bx = r & 15;
  const int bm = by * 128, bn = bx * 128;
  f32x4 acc[4][4];
  gemm3r<32>(qb + b * (SEQ * DM) + bm * 1024,
             kb + b * (SEQ * DM) + bn * 1024, 1024, 1024, lds, acc, tid);
  u16* out = sb + (size_t)b * SEQ * SEQ;
  const int l = tid & 63, w = tid >> 6;
  const int wm = w >> 1, wn = w & 1;
#pragma unroll
  for (int m = 0; m < 4; ++m)
#pragma unroll
    for (int n = 0; n < 4; ++n) {
      int col = bn + wn * 64 + n * 16 + (l & 15);
#pragma unroll
      for (int j = 0; j < 4; ++j) {
        int row = bm + wm * 64 + m * 16 + (l >> 4) * 4 + j;
        out[row * 2048 + col] = f2b(acc[m][n][j] * 0.03125f);
      }
    }
}

// ---------- row softmax: 2048-wide rows, bf16 in, bf16 out ----------
__global__ __launch_bounds__(256) void softmax_k(const u16* __restrict__ sb,
                                                 u16* __restrict__ pb) {
  __shared__ float red[8];
  int row = blockIdx.x;
  const u16* src = sb + (size_t)row * 2048;
  u16* dst = pb + (size_t)row * 2048;
  int t = threadIdx.x;
  uint4 raw = *(const uint4*)(src + t * 8);
  uint32_t rw[4] = {raw.x, raw.y, raw.z, raw.w};
  float v[8];
#pragma unroll
  for (int q = 0; q < 4; ++q) {
    v[2 * q]     = b2f(rw[q] & 0xFFFFu);
    v[2 * q + 1] = __builtin_bit_cast(float, rw[q] & 0xFFFF0000u);
  }
  float m = v[0];
#pragma unroll
  for (int j = 1; j < 8; ++j) m = fmaxf(m, v[j]);
  for (int off = 32; off; off >>= 1) m = fmaxf(m, __shfl_xor(m, off));
  int w = t >> 6, l = t & 63;
  if (l == 0) red[w] = m;
  __syncthreads();
  m = fmaxf(fmaxf(red[0], red[1]), fmaxf(red[2], red[3]));
  float e[8], s = 0.f;
#pragma unroll
  for (int j = 0; j < 8; ++j) { e[j] = __expf(v[j] - m); s += e[j]; }
  for (int off = 32; off; off >>= 1) s += __shfl_xor(s, off);
  if (l == 0) red[4 + w] = s;
  __syncthreads();
  s = (red[4] + red[5]) + (red[6] + red[7]);
  float inv = 1.0f / s;
  uint32_t o[4];
#pragma unroll
  for (int q = 0; q < 4; ++q) {
    uint32_t lo = f2b(e[2 * q] * inv);
    uint32_t hi = f2b(e[2 * q + 1] * inv);
    o[q] = lo | (hi << 16);
  }
  *(uint4*)(dst + t * 8) = make_uint4(o[0], o[1], o[2], o[3]);
}

// ---------- PV GEMM per batch: out = pb[2048x2048] * v[2048x1024], fp32 out ----------
// Grid 512 = 4 batches x 16 x 8; XCD swizzle (512 = 8*64).
__global__ __launch_bounds__(256, 3) void pv_gemm(const u16* __restrict__ pb,
                                                  const u16* __restrict__ vtb,
                                                  float* __restrict__ out) {
  __shared__ __align__(16) char lds[49152];
  const int tid = threadIdx.x;
  const int lin = blockIdx.x;
  const int wgid = (lin & 7) * 64 + (lin >> 3);
  const int b = wgid >> 7, r = wgid & 127;
  const int by = r >> 3, bx = r & 7;
  const int bm = by * 128, bn = bx * 128;
  f32x4 acc[4][4];
  gemm3r<64>(pb + (size_t)b * SEQ * SEQ + bm * 2048,
             vtb + (size_t)b * DM * SEQ + bn * 2048, 2048, 2048, lds, acc, tid);
  float* o = out + (size_t)b * SEQ * DM;
  const int l = tid & 63, w = tid >> 6;
  const int wm = w >> 1, wn = w & 1;
#pragma unroll
  for (int m = 0; m < 4; ++m)
#pragma unroll
    for (int n = 0; n < 4; ++n) {
      int col = bn + wn * 64 + n * 16 + (l & 15);
#pragma unroll
      for (int j = 0; j < 4; ++j) {
        int row = bm + wm * 64 + m * 16 + (l >> 4) * 4 + j;
        o[row * 1024 + col] = acc[m][n][j];
      }
    }
}

// ---------- launch ----------
extern "C" void kernel_launch(void* const* d_in, const int* in_sizes, int n_in,
                              void* d_out, int out_size, void* d_ws, size_t ws_size,
                              hipStream_t stream) {
  const float* x  = (const float*)d_in[0];
  const float* Wq = (const float*)d_in[1];
  const float* bq = (const float*)d_in[2];
  const float* Wk = (const float*)d_in[3];
  const float* bk = (const float*)d_in[4];
  const float* Wv = (const float*)d_in[5];
  const float* bv = (const float*)d_in[6];
  float* out = (float*)d_out;

  char* ws = (char*)d_ws;
  u16* xb   = (u16*)(ws);                 // 16 MB  bf16 x            [8192][1024]
  u16* wcat = (u16*)(ws + 16777216);      //  6 MB  bf16 Wq|Wk|Wv     [3072][1024]
  u16* qb   = (u16*)(ws + 23068672);      // 16 MB  bf16 q            [4][2048][1024]
  u16* kb   = (u16*)(ws + 39845888);      // 16 MB  bf16 k            [4][2048][1024]
  u16* vtb  = (u16*)(ws + 56623104);      // 16 MB  bf16 v^T          [4][1024][2048]
  u16* sb   = (u16*)(ws + 73400320);      // 32 MB  bf16 scores       [4][2048][2048]
  u16* pb   = (u16*)(ws + 106954752);     // 32 MB  bf16 probs        [4][2048][2048]

  cvt_x_kernel<<<8192, 256, 0, stream>>>(x, xb);
  pack_w_kernel<<<3072, 256, 0, stream>>>(Wq, Wk, Wv, wcat);
  qkv_gemm<<<1536, 256, 0, stream>>>(xb, wcat, bq, bk, bv, qb, kb, vtb);
  scores_gemm<<<1024, 256, 0, stream>>>(qb, kb, sb);
  softmax_k<<<8192, 256, 0, stream>>>(sb, pb);
  pv_gemm<<<512, 256, 0, stream>>>(pb, vtb, out);
}

// Round 10
// 177.585 us; speedup vs baseline: 1.0835x; 1.0835x over previous
//
#include <hip/hip_runtime.h>
#include <cstdint>

// Fused single-head attention, B=4 S=2048 D=1024, fp32 in/out, bf16 MFMA compute.
// Pipeline: cast/pack -> QKV GEMM (v transposed) -> scores GEMM -> softmax -> PV GEMM.
// R10 = R9 with the gemm_core call-site arity fixed (K,lda,ldb all passed).
// R1 engine verbatim (session-best: qkv 77us, 0 bank conflicts, natural
// dispatch order) + coalesced LDS-bounce epilogues for bf16 tiles (qkv q/k,
// scores): acc -> LDS (chunk-XOR layout, <=2-way aliasing) -> uint4 row-linear
// global stores (16B/lane full-line), replacing 64 scalar 2B stores/thread.
// Converts merged into one launch.

typedef unsigned short u16;
typedef __attribute__((ext_vector_type(4))) float f32x4;
typedef __attribute__((ext_vector_type(8))) __bf16 bf16x8;

#define AS1(p) ((const __attribute__((address_space(1))) void*)(p))
#define AS3(p) ((__attribute__((address_space(3))) void*)(p))

#define SEQ 2048
#define DM 1024

// ---------- bf16 bit helpers ----------
__device__ __forceinline__ u16 f2b(float f) {
  uint32_t u = __builtin_bit_cast(uint32_t, f);
  u += 0x7FFFu + ((u >> 16) & 1u);   // RNE
  return (u16)(u >> 16);
}
__device__ __forceinline__ float b2f(uint32_t bits16) {
  return __builtin_bit_cast(float, bits16 << 16);
}

// ---------- fused converts: x -> xb, Wq|Wk|Wv -> wcat ----------
__global__ __launch_bounds__(256) void cvt_all(const float* __restrict__ x,
                                               const float* __restrict__ Wq,
                                               const float* __restrict__ Wk,
                                               const float* __restrict__ Wv,
                                               u16* __restrict__ xb,
                                               u16* __restrict__ wcat) {
  const int bid = blockIdx.x;
  const float* src;
  u16* dst;
  int i;
  if (bid < 8192) {                      // x: 8192*1024 fp32
    i = (bid * 256 + threadIdx.x) * 4;
    src = x; dst = xb;
  } else {                               // weights: 3*2^20 fp32
    i = ((bid - 8192) * 256 + threadIdx.x) * 4;
    dst = wcat;
    if (i < (1 << 20))      { src = Wq; }
    else if (i < (2 << 20)) { src = Wk; i -= (1 << 20); dst = wcat + (1 << 20); }
    else                    { src = Wv; i -= (2 << 20); dst = wcat + (2 << 20); }
  }
  float4 v = *(const float4*)(src + i);
  ushort4 o;
  o.x = f2b(v.x); o.y = f2b(v.y); o.z = f2b(v.z); o.w = f2b(v.w);
  *(ushort4*)(dst + i) = o;
}

// ---------- GEMM core (R1 verbatim): C[128x128] += A[128xK] * Bt[128xK]^T ----------
// LDS tile [128 rows][64 cols] bf16 = 16 KB, XOR-swizzled 16B chunks within
// each 128B row: physical_chunk = logical_chunk ^ (row & 7).  global_load_lds
// writes LDS linearly, so the global source is inverse-swizzled (rule 21),
// and ds_read applies the same XOR.  Measured 0 bank conflicts.
#define BK 64

__device__ __forceinline__ void stage_tile(const u16* __restrict__ g, int ld,
                                           char* lds, int tid) {
  int w = tid >> 6, l = tid & 63;
#pragma unroll
  for (int p = 0; p < 4; ++p) {
    int o  = p * 4096 + w * 1024 + l * 16;   // linear LDS byte offset
    int r  = o >> 7;                          // row (128B per row)
    int pc = (o >> 4) & 7;                    // physical 16B chunk
    int lc = pc ^ (r & 7);                    // logical chunk to fetch
    const u16* src = g + r * ld + lc * 8;
    char* dst = lds + p * 4096 + w * 1024;    // wave-uniform base; HW adds lane*16
    __builtin_amdgcn_global_load_lds(AS1(src), AS3(dst), 16, 0, 0);
  }
}

__device__ __forceinline__ bf16x8 read_frag(const char* lds, int row, int kk) {
  int lc  = kk >> 3;
  int off = row * 128 + ((lc ^ (row & 7)) << 4);
  return *(const bf16x8*)(lds + off);
}

__device__ __forceinline__ void gemm_core(const u16* __restrict__ A,
                                          const u16* __restrict__ Bt,
                                          int K, int lda, int ldb,
                                          char* ldsA, char* ldsB,
                                          f32x4 acc[4][4], int tid) {
  int w = tid >> 6, l = tid & 63;
  int wm = (w >> 1) * 64, wn = (w & 1) * 64;
  int fr = l & 15, fk = (l >> 4) * 8;
  for (int k0 = 0; k0 < K; k0 += BK) {
    stage_tile(A + k0, lda, ldsA, tid);
    stage_tile(Bt + k0, ldb, ldsB, tid);
    __syncthreads();
#pragma unroll
    for (int ks = 0; ks < 2; ++ks) {
      bf16x8 af[4], bfr[4];
#pragma unroll
      for (int m = 0; m < 4; ++m) af[m]  = read_frag(ldsA, wm + m * 16 + fr, ks * 32 + fk);
#pragma unroll
      for (int n = 0; n < 4; ++n) bfr[n] = read_frag(ldsB, wn + n * 16 + fr, ks * 32 + fk);
#pragma unroll
      for (int m = 0; m < 4; ++m)
#pragma unroll
        for (int n = 0; n < 4; ++n)
          acc[m][n] = __builtin_amdgcn_mfma_f32_16x16x32_bf16(af[m], bfr[n], acc[m][n], 0, 0, 0);
    }
    __syncthreads();
  }
}

#define ZERO_ACC(acc)                                     \
  _Pragma("unroll") for (int m_ = 0; m_ < 4; ++m_)        \
  _Pragma("unroll") for (int n_ = 0; n_ < 4; ++n_)        \
  _Pragma("unroll") for (int j_ = 0; j_ < 4; ++j_)        \
      acc[m_][n_][j_] = 0.f;

// ---------- QKV GEMM: [8192 x 3072] = xb[8192x1024] * wcat[3072x1024]^T + bias ----------
__global__ __launch_bounds__(256, 2) void qkv_gemm(const u16* __restrict__ xb,
                                                   const u16* __restrict__ wcat,
                                                   const float* __restrict__ bq,
                                                   const float* __restrict__ bk,
                                                   const float* __restrict__ bv,
                                                   u16* __restrict__ qb,
                                                   u16* __restrict__ kb,
                                                   u16* __restrict__ vtb) {
  __shared__ __align__(16) char lds[32768];
  int tid = threadIdx.x;
  int bm = blockIdx.y * 128, bn = blockIdx.x * 128;
  f32x4 acc[4][4];
  ZERO_ACC(acc);
  gemm_core(xb + bm * 1024, wcat + bn * 1024, 1024, 1024, 1024,
            lds, lds + 16384, acc, tid);
  int w = tid >> 6, l = tid & 63;
  int wm = (w >> 1) * 64, wn = (w & 1) * 64;
  int which = bn >> 10;  // uniform per block (128 | 1024)
  if (which == 2) {
    // v: write transposed [e][s] (scatter; same as R1)
    const float* bias = bv;
#pragma unroll
    for (int m = 0; m < 4; ++m)
#pragma unroll
      for (int n = 0; n < 4; ++n) {
        int col = bn + wn + n * 16 + (l & 15);
        int e = col & 1023;
        float bval = bias[e];
#pragma unroll
        for (int j = 0; j < 4; ++j) {
          int row = bm + wm + m * 16 + (l >> 4) * 4 + j;
          int b = row >> 11, s = row & 2047;
          vtb[(b << 21) + e * 2048 + s] = f2b(acc[m][n][j] + bval);
        }
      }
  } else {
    u16* outp = (which == 0) ? qb : kb;
    const float* bias = (which == 0) ? bq : bk;
    const int ebase = bn & 1023;
    __syncthreads();   // gemm_core's last barrier already passed; LDS reuse safe,
                       // but keep reads (MFMA frags) strictly before overwrite.
    // E1: acc -> LDS (chunk-XOR layout)
#pragma unroll
    for (int m = 0; m < 4; ++m)
#pragma unroll
      for (int n = 0; n < 4; ++n) {
        int cl = wn + n * 16 + (l & 15);
        float bval = bias[ebase + cl];
#pragma unroll
        for (int j = 0; j < 4; ++j) {
          int rl = wm + m * 16 + (l >> 4) * 4 + j;
          int chunk = (cl >> 3) ^ (rl & 7);
          *(u16*)(lds + rl * 256 + chunk * 16 + (cl & 7) * 2) = f2b(acc[m][n][j] + bval);
        }
      }
    __syncthreads();
    // E3: row-linear uint4 stores
#pragma unroll
    for (int p = 0; p < 8; ++p) {
      int rl = p * 16 + (tid >> 4);
      int c  = tid & 15;
      int phys = c ^ (rl & 7);
      uint4 v = *(const uint4*)(lds + rl * 256 + phys * 16);
      *(uint4*)(outp + (size_t)(bm + rl) * 1024 + ebase + c * 8) = v;
    }
  }
}

// ---------- scores GEMM per batch: sb = (q * k^T) / 32, bf16 ----------
__global__ __launch_bounds__(256, 2) void scores_gemm(const u16* __restrict__ qb,
                                                      const u16* __restrict__ kb,
                                                      u16* __restrict__ sb) {
  __shared__ __align__(16) char lds[32768];
  int tid = threadIdx.x;
  int b = blockIdx.z;
  int bm = blockIdx.y * 128, bn = blockIdx.x * 128;
  f32x4 acc[4][4];
  ZERO_ACC(acc);
  gemm_core(qb + b * (SEQ * DM) + bm * 1024,
            kb + b * (SEQ * DM) + bn * 1024, 1024, 1024, 1024,
            lds, lds + 16384, acc, tid);
  u16* out = sb + (size_t)b * SEQ * SEQ;
  int w = tid >> 6, l = tid & 63;
  int wm = (w >> 1) * 64, wn = (w & 1) * 64;
  __syncthreads();
  // E1
#pragma unroll
  for (int m = 0; m < 4; ++m)
#pragma unroll
    for (int n = 0; n < 4; ++n) {
      int cl = wn + n * 16 + (l & 15);
#pragma unroll
      for (int j = 0; j < 4; ++j) {
        int rl = wm + m * 16 + (l >> 4) * 4 + j;
        int chunk = (cl >> 3) ^ (rl & 7);
        *(u16*)(lds + rl * 256 + chunk * 16 + (cl & 7) * 2) = f2b(acc[m][n][j] * 0.03125f);
      }
    }
  __syncthreads();
  // E3
#pragma unroll
  for (int p = 0; p < 8; ++p) {
    int rl = p * 16 + (tid >> 4);
    int c  = tid & 15;
    int phys = c ^ (rl & 7);
    uint4 v = *(const uint4*)(lds + rl * 256 + phys * 16);
    *(uint4*)(out + (size_t)(bm + rl) * 2048 + bn + c * 8) = v;
  }
}

// ---------- row softmax: 2048-wide rows, bf16 in, bf16 out ----------
__global__ __launch_bounds__(256) void softmax_k(const u16* __restrict__ sb,
                                                 u16* __restrict__ pb) {
  __shared__ float red[8];
  int row = blockIdx.x;
  const u16* src = sb + (size_t)row * 2048;
  u16* dst = pb + (size_t)row * 2048;
  int t = threadIdx.x;
  uint4 raw = *(const uint4*)(src + t * 8);
  uint32_t rw[4] = {raw.x, raw.y, raw.z, raw.w};
  float v[8];
#pragma unroll
  for (int q = 0; q < 4; ++q) {
    v[2 * q]     = b2f(rw[q] & 0xFFFFu);
    v[2 * q + 1] = __builtin_bit_cast(float, rw[q] & 0xFFFF0000u);
  }
  float m = v[0];
#pragma unroll
  for (int j = 1; j < 8; ++j) m = fmaxf(m, v[j]);
  for (int off = 32; off; off >>= 1) m = fmaxf(m, __shfl_xor(m, off));
  int w = t >> 6, l = t & 63;
  if (l == 0) red[w] = m;
  __syncthreads();
  m = fmaxf(fmaxf(red[0], red[1]), fmaxf(red[2], red[3]));
  float e[8], s = 0.f;
#pragma unroll
  for (int j = 0; j < 8; ++j) { e[j] = __expf(v[j] - m); s += e[j]; }
  for (int off = 32; off; off >>= 1) s += __shfl_xor(s, off);
  if (l == 0) red[4 + w] = s;
  __syncthreads();
  s = (red[4] + red[5]) + (red[6] + red[7]);
  float inv = 1.0f / s;
  uint32_t o[4];
#pragma unroll
  for (int q = 0; q < 4; ++q) {
    uint32_t lo = f2b(e[2 * q] * inv);
    uint32_t hi = f2b(e[2 * q + 1] * inv);
    o[q] = lo | (hi << 16);
  }
  *(uint4*)(dst + t * 8) = make_uint4(o[0], o[1], o[2], o[3]);
}

// ---------- PV GEMM per batch: out = pb[2048x2048] * v[2048x1024], fp32 out ----------
__global__ __launch_bounds__(256, 2) void pv_gemm(const u16* __restrict__ pb,
                                                  const u16* __restrict__ vtb,
                                                  float* __restrict__ out) {
  __shared__ __align__(16) char lds[32768];
  int tid = threadIdx.x;
  int b = blockIdx.z;
  int bm = blockIdx.y * 128, bn = blockIdx.x * 128;
  f32x4 acc[4][4];
  ZERO_ACC(acc);
  gemm_core(pb  + (size_t)b * SEQ * SEQ + bm * 2048,
            vtb + (size_t)b * DM * SEQ  + bn * 2048, 2048, 2048, 2048,
            lds, lds + 16384, acc, tid);
  float* o = out + (size_t)b * SEQ * DM;
  int w = tid >> 6, l = tid & 63;
  int wm = (w >> 1) * 64, wn = (w & 1) * 64;
#pragma unroll
  for (int m = 0; m < 4; ++m)
#pragma unroll
    for (int n = 0; n < 4; ++n) {
      int col = bn + wn + n * 16 + (l & 15);
#pragma unroll
      for (int j = 0; j < 4; ++j) {
        int row = bm + wm + m * 16 + (l >> 4) * 4 + j;
        o[row * 1024 + col] = acc[m][n][j];
      }
    }
}

// ---------- launch ----------
extern "C" void kernel_launch(void* const* d_in, const int* in_sizes, int n_in,
                              void* d_out, int out_size, void* d_ws, size_t ws_size,
                              hipStream_t stream) {
  const float* x  = (const float*)d_in[0];
  const float* Wq = (const float*)d_in[1];
  const float* bq = (const float*)d_in[2];
  const float* Wk = (const float*)d_in[3];
  const float* bk = (const float*)d_in[4];
  const float* Wv = (const float*)d_in[5];
  const float* bv = (const float*)d_in[6];
  float* out = (float*)d_out;

  char* ws = (char*)d_ws;
  u16* xb   = (u16*)(ws);                 // 16 MB  bf16 x            [8192][1024]
  u16* wcat = (u16*)(ws + 16777216);      //  6 MB  bf16 Wq|Wk|Wv     [3072][1024]
  u16* qb   = (u16*)(ws + 23068672);      // 16 MB  bf16 q            [4][2048][1024]
  u16* kb   = (u16*)(ws + 39845888);      // 16 MB  bf16 k            [4][2048][1024]
  u16* vtb  = (u16*)(ws + 56623104);      // 16 MB  bf16 v^T          [4][1024][2048]
  u16* sb   = (u16*)(ws + 73400320);      // 32 MB  bf16 scores       [4][2048][2048]
  u16* pb   = (u16*)(ws + 106954752);     // 32 MB  bf16 probs        [4][2048][2048]

  cvt_all<<<11264, 256, 0, stream>>>(x, Wq, Wk, Wv, xb, wcat);
  qkv_gemm<<<dim3(24, 64), 256, 0, stream>>>(xb, wcat, bq, bk, bv, qb, kb, vtb);
  scores_gemm<<<dim3(16, 16, 4), 256, 0, stream>>>(qb, kb, sb);
  softmax_k<<<8192, 256, 0, stream>>>(sb, pb);
  pv_gemm<<<dim3(8, 16, 4), 256, 0, stream>>>(pb, vtb, out);
}